// Round 8
// baseline (924.074 us; speedup 1.0000x reference)
//
#include <hip/hip_runtime.h>
#include <hip/hip_bf16.h>

// ExpansionContrastModule on MI355X.
// ROUND 8: DIAGNOSTIC round. Structure identical to passing round-7 (3 launches,
// kv in d_out[0,1MB), srraw ws[0,6144), v ws[532480,...)), but each kernel's core
// work runs DIAG_REPS=8x (opaque base pointers via asm "+s" force real re-loads;
// asm "+v" keepers prevent DCE; stores idempotent/final-rep -> outputs identical).
// Purpose: push all three kernels above the ~45us fillBuffer floor so they appear
// in rocprof top-5 WITH counters, giving the first per-kernel time/bottleneck
// attribution. dur_us will be ~8x (expected, reverted next round).

#define CC 32
#define HW 256
#define KVW 64
#define DIAG_REPS 8

// ---------------- K1: 5x5 stride-4 pad-2 conv + bias -> kv [2,32,64,64] ----------------
__global__ __launch_bounds__(256, 2) void k1_trans(const float* __restrict__ cen,
                                                   const float* __restrict__ tW,
                                                   const float* __restrict__ tB,
                                                   float* __restrict__ kv) {
  __shared__ alignas(16) float part[4][4][64];  // [ci-quarter][co][x], 4 KB
  int bid = blockIdx.x;
  int b = bid >> 9, cog = (bid >> 6) & 7, y = bid & 63;
  int tid = threadIdx.x;
  int x = tid & 63;
  int w = __builtin_amdgcn_readfirstlane(tid >> 6);  // wave id 0..3 = ci quarter
  int ci0 = w * 8;
  int co0 = cog * 4;

  const float4 z4 = {0.f, 0.f, 0.f, 0.f};
  int roff[5];
  bool rok[5];
#pragma unroll
  for (int r = 0; r < 5; r++) {
    int row = 4 * y - 2 + r;
    rok[r] = (row >= 0);
    roff[r] = (row < 0 ? 0 : row) * HW;
  }

  float acc[4];
  const float* cenp = cen;
  const float* tWp = tW;
#pragma unroll 1
  for (int rep = 0; rep < DIAG_REPS; rep++) {
    asm volatile("" : "+s"(cenp), "+s"(tWp));  // opaque -> reload each rep
    acc[0] = acc[1] = acc[2] = acc[3] = 0.f;
    for (int cc4 = 0; cc4 < 8; cc4 += 4) {
      int ci = ci0 + cc4;
      const float* pc[4];
#pragma unroll
      for (int c = 0; c < 4; c++)
        pc[c] = cenp + (size_t)(b * CC + ci + c) * 65536 + 4 * x;
      float4 A[4][5], B[4][5];
#pragma unroll
      for (int c = 0; c < 4; c++) {
#pragma unroll
        for (int r = 0; r < 5; r++) {
          A[c][r] = (x > 0) ? *(const float4*)(pc[c] + roff[r] - 4) : z4;
          B[c][r] = *(const float4*)(pc[c] + roff[r]);
        }
      }
#pragma unroll
      for (int r = 0; r < 5; r++) {
        if (!rok[r]) continue;  // block-uniform (only y==0, r<2)
#pragma unroll
        for (int c = 0; c < 4; c++) {
#pragma unroll
          for (int co = 0; co < 4; co++) {
            const float* wa = tWp + ((co0 + co) * CC + ci + c) * 25 + r * 5;
            acc[co] += wa[0] * A[c][r].z + wa[1] * A[c][r].w + wa[2] * B[c][r].x +
                       wa[3] * B[c][r].y + wa[4] * B[c][r].z;
          }
        }
      }
    }
    asm volatile("" : "+v"(acc[0]), "+v"(acc[1]), "+v"(acc[2]), "+v"(acc[3]));
  }

#pragma unroll
  for (int co = 0; co < 4; co++) part[w][co][x] = acc[co];
  __syncthreads();
  {
    int co = tid >> 6, xx = tid & 63;
    float s = part[0][co][xx] + part[1][co][xx] + part[2][co][xx] + part[3][co][xx];
    kv[((b * CC + co0 + co) * KVW + y) * KVW + xx] = s + tB[co0 + co];
  }
}

// ---------------- K23 fat: blocks 0..191 = K2i body; 192..447 = K3a body -------------
__device__ inline float wred64(float v) {
#pragma unroll
  for (int off = 1; off < 64; off <<= 1) v += __shfl_xor(v, off);
  return v;
}

__global__ __launch_bounds__(1024) void k23_fat(const float* __restrict__ kv,
                                                const float* __restrict__ qW,
                                                const float* __restrict__ kW,
                                                float* __restrict__ srraw,
                                                const float* __restrict__ cen,
                                                const float* __restrict__ vW,
                                                __hip_bfloat16* __restrict__ v) {
  __shared__ alignas(16) float kl[4096];
  __shared__ float wredl[16][18];
  int bid = blockIdx.x;
  int tid = threadIdx.x;

  if (bid < 192) {
    int bc = bid / 3, i = bid - bc * 3;
    int b = bc >> 5, c = bc & 31;
    int lane = tid & 63, w = tid >> 6;
    int xx = tid & 63;
    int ybase = tid >> 6;

    const float* kvp = kv;
    const float* qWp = qW;
    const float* kWp = kW;
#pragma unroll 1
    for (int rep = 0; rep < DIAG_REPS; rep++) {
      asm volatile("" : "+s"(kvp), "+s"(qWp), "+s"(kWp));
      float qreg[4];
#pragma unroll
      for (int r = 0; r < 4; r++) {
        int px = r * 1024 + tid;
        float q = 0.f, kk = 0.f;
        for (int ci = 0; ci < CC; ci++) {
          float val = kvp[(b * CC + ci) * 4096 + px];
          q += qWp[c * CC + ci] * val;
          kk += kWp[(i * CC + c) * CC + ci] * val;
        }
        qreg[r] = q;
        kl[px] = kk;
      }
      __syncthreads();

      float q2 = 0.f;
#pragma unroll
      for (int r = 0; r < 4; r++) q2 += qreg[r] * qreg[r];
      q2 = wred64(q2);
      if (lane == 0) wredl[w][16] = q2;

      constexpr int DYt[8] = {-1, -1, -1, 0, 1, 1, 1, 0};
      constexpr int DXt[8] = {-1, 0, 1, 1, 1, 0, -1, -1};
      const int d = 1 << i;
#pragma unroll
      for (int n = 0; n < 8; n++) {
        const int dy = DYt[n], dx = DXt[n];
        int xn = xx + dx * d;
        bool xok = (xn >= 0 && xn < KVW);
        float dacc = 0.f, macc = 0.f;
#pragma unroll
        for (int r = 0; r < 4; r++) {
          int yy = r * 16 + ybase;
          int px = yy * KVW + xx;
          float kc = kl[px];
          int yn = yy + dy * d;
          float kn = (xok && yn >= 0 && yn < KVW) ? kl[yn * KVW + xn] : 0.f;
          float df = kc - kn;
          dacc += qreg[r] * df;
          macc += df * df;
        }
        dacc = wred64(dacc);
        macc = wred64(macc);
        if (lane == 0) {
          wredl[w][n] = dacc;
          wredl[w][8 + n] = macc;
        }
      }
      __syncthreads();

      if (tid < 8) {
        float D = 0.f, M = 0.f, Q = 0.f;
        for (int w2 = 0; w2 < 16; w2++) {
          D += wredl[w2][tid];
          M += wredl[w2][8 + tid];
          Q += wredl[w2][16];
        }
        float sr = D / (fmaxf(sqrtf(M), 1e-12f) * fmaxf(sqrtf(Q), 1e-12f));
        srraw[bc * 24 + i * 8 + tid] = sr;  // idempotent across reps
      }
      __syncthreads();  // orders rep N's wredl reads vs rep N+1's writes
    }
  } else {
    int bid2 = bid - 192;
    int vb = bid2 * 4 + (tid >> 8);
    int b = vb >> 9, blk = vb & 511;
    int lane = tid & 63;
    int cg = __builtin_amdgcn_readfirstlane((tid >> 6) & 3);
    int px = blk * 128 + lane * 2;

    const float* cenp = cen;
    const float* vWp = vW;
#pragma unroll 1
    for (int rep = 0; rep < DIAG_REPS; rep++) {
      asm volatile("" : "+s"(cenp), "+s"(vWp));
      float2 cr[CC];
#pragma unroll
      for (int ci = 0; ci < CC; ci++)
        cr[ci] = *(const float2*)(cenp + (size_t)(b * CC + ci) * 65536 + px);

#pragma unroll
      for (int i = 0; i < 3; i++) {
#pragma unroll
        for (int cc = 0; cc < 8; cc++) {
          int c = cg * 8 + cc;
          const float* wp = vWp + (i * CC + c) * CC;
          float a0 = 0.f, a1 = 0.f;
#pragma unroll
          for (int ci = 0; ci < CC; ci++) {
            a0 += wp[ci] * cr[ci].x;
            a1 += wp[ci] * cr[ci].y;
          }
          __hip_bfloat16 h0 = __float2bfloat16(a0);
          __hip_bfloat16 h1 = __float2bfloat16(a1);
          unsigned int pk = (unsigned int)(*(unsigned short*)&h0) |
                            ((unsigned int)(*(unsigned short*)&h1) << 16);
          if (rep == DIAG_REPS - 1) {
            *(unsigned int*)((unsigned short*)v +
                             (((size_t)((i * 2 + b) * CC + c)) << 16) + px) = pk;
          } else {
            asm volatile("" :: "v"(pk));  // keep rep live without extra writes
          }
        }
      }
    }
  }
}

// ---------------- K3b: score l2norm + combine + out conv + BN + ReLU -----
__global__ __launch_bounds__(256) void k3b_combine(const __hip_bfloat16* __restrict__ v,
                                                   const float* __restrict__ srraw,
                                                   const float* __restrict__ oW,
                                                   const float* __restrict__ gamma,
                                                   const float* __restrict__ beta,
                                                   const float* __restrict__ mean,
                                                   const float* __restrict__ var,
                                                   float* __restrict__ out) {
  __shared__ alignas(16) float vt[3 * 24 * 24 * 4];
  __shared__ alignas(16) float sl[27][32];
  __shared__ alignas(16) float owl[32][32];
  __shared__ float bns[32], bnb[32];

  int bid = blockIdx.x;
  int b = bid >> 8, tile = bid & 255;
  int ty = tile >> 4, tx = tile & 15;
  int tid = threadIdx.x;
  int ly = tid >> 4, lx = tid & 15;

  for (int f = tid; f < 768; f += 256) {
    int j = f >> 5, c = f & 31;
    sl[j][c] = srraw[(b * CC + c) * 24 + j];
  }
  for (int f = tid; f < 1024; f += 256) owl[f >> 5][f & 31] = oW[f];
  if (tid < 32) {
    float inv = rsqrtf(var[tid] + 1e-5f);
    float sc = gamma[tid] * inv;
    bns[tid] = sc;
    bnb[tid] = beta[tid] - mean[tid] * sc;
  }
  __syncthreads();
  if (tid < 32) {
    float r2 = 0.f;
#pragma unroll
    for (int j = 0; j < 24; j++) {
      float s = sl[j][tid];
      r2 += s * s;
    }
    float dn = fmaxf(sqrtf(r2), 1e-12f);
#pragma unroll
    for (int j = 0; j < 24; j++) sl[j][tid] /= dn;
#pragma unroll
    for (int i = 0; i < 3; i++) {
      float s = 0.f;
      for (int n = 0; n < 8; n++) s += sl[i * 8 + n][tid];
      sl[24 + i][tid] = s;
    }
  }

  int ldsoff[4], pxoff[4], ibase[4];
  bool okp[4];
#pragma unroll
  for (int it = 0; it < 4; it++) {
    int p = tid + it * 256;
    bool act = (p < 864);
    int pp = act ? p : 0;
    int i = pp / 288;
    int rem = pp - i * 288;
    int r = rem / 12;
    int col = (rem - r * 12) * 2;
    int gy = ty * 16 + r - 4, gx = tx * 16 + col - 4;
    okp[it] = act && gy >= 0 && gy < HW && gx >= 0 && gx < HW;
    pxoff[it] = gy * HW + gx;
    ibase[it] = (i * 2 + b) * CC;
    ldsoff[it] = ((i * 24 + r) * 24 + col) * 4;
  }

  constexpr int DYt[8] = {-1, -1, -1, 0, 1, 1, 1, 0};
  constexpr int DXt[8] = {-1, 0, 1, 1, 1, 0, -1, -1};

  float acc[32];
  const unsigned short* vs = (const unsigned short*)v;
  unsigned int pf[4][4];

#pragma unroll 1
  for (int rep = 0; rep < DIAG_REPS; rep++) {
    asm volatile("" : "+s"(vs));  // opaque -> re-load v each rep
#pragma unroll
    for (int co = 0; co < 32; co++) acc[co] = 0.f;

#pragma unroll
    for (int it = 0; it < 4; it++)
#pragma unroll
      for (int cp = 0; cp < 4; cp++)
        pf[it][cp] = okp[it] ? *(const unsigned int*)(vs +
                                                      (((size_t)(ibase[it] + cp)) << 16) +
                                                      pxoff[it])
                             : 0u;

    for (int cg = 0; cg < 8; cg++) {
      __syncthreads();
#pragma unroll
      for (int it = 0; it < 4; it++) {
        if (it == 3 && tid >= 96) continue;
        float4 lo, hi;
        lo.x = __uint_as_float(pf[it][0] << 16);
        lo.y = __uint_as_float(pf[it][1] << 16);
        lo.z = __uint_as_float(pf[it][2] << 16);
        lo.w = __uint_as_float(pf[it][3] << 16);
        hi.x = __uint_as_float(pf[it][0] & 0xffff0000u);
        hi.y = __uint_as_float(pf[it][1] & 0xffff0000u);
        hi.z = __uint_as_float(pf[it][2] & 0xffff0000u);
        hi.w = __uint_as_float(pf[it][3] & 0xffff0000u);
        *(float4*)&vt[ldsoff[it]] = lo;
        *(float4*)&vt[ldsoff[it] + 4] = hi;
      }
      if (cg < 7) {
        int cb = (cg + 1) * 4;
#pragma unroll
        for (int it = 0; it < 4; it++)
#pragma unroll
          for (int cp = 0; cp < 4; cp++)
            pf[it][cp] = okp[it]
                             ? *(const unsigned int*)(vs +
                                                      (((size_t)(ibase[it] + cb + cp))
                                                       << 16) +
                                                      pxoff[it])
                             : 0u;
      }
      __syncthreads();

      float4 pre = {0.f, 0.f, 0.f, 0.f};
#pragma unroll
      for (int i = 0; i < 3; i++) {
        const int d = 1 << i;
        float4 S4 = *(const float4*)&sl[24 + i][cg * 4];
        float4 ctr = *(const float4*)&vt[((i * 24 + (ly + 4)) * 24 + (lx + 4)) * 4];
        pre.x += S4.x * ctr.x;
        pre.y += S4.y * ctr.y;
        pre.z += S4.z * ctr.z;
        pre.w += S4.w * ctr.w;
#pragma unroll
        for (int n = 0; n < 8; n++) {
          float4 sj = *(const float4*)&sl[i * 8 + n][cg * 4];
          float4 nb = *(const float4*)&vt[((i * 24 + (ly + 4 + DYt[n] * d)) * 24 +
                                           (lx + 4 + DXt[n] * d)) * 4];
          pre.x -= sj.x * nb.x;
          pre.y -= sj.y * nb.y;
          pre.z -= sj.z * nb.z;
          pre.w -= sj.w * nb.w;
        }
      }
#pragma unroll
      for (int co = 0; co < 32; co++) {
        float4 ow = *(const float4*)&owl[co][cg * 4];
        acc[co] += ow.x * pre.x + ow.y * pre.y + ow.z * pre.z + ow.w * pre.w;
      }
    }
    // keep acc live across reps (prevents DCE of non-final reps)
    asm volatile("" : "+v"(acc[0]), "+v"(acc[1]), "+v"(acc[2]), "+v"(acc[3]),
                     "+v"(acc[4]), "+v"(acc[5]), "+v"(acc[6]), "+v"(acc[7]));
    asm volatile("" : "+v"(acc[8]), "+v"(acc[9]), "+v"(acc[10]), "+v"(acc[11]),
                     "+v"(acc[12]), "+v"(acc[13]), "+v"(acc[14]), "+v"(acc[15]));
    asm volatile("" : "+v"(acc[16]), "+v"(acc[17]), "+v"(acc[18]), "+v"(acc[19]),
                     "+v"(acc[20]), "+v"(acc[21]), "+v"(acc[22]), "+v"(acc[23]));
    asm volatile("" : "+v"(acc[24]), "+v"(acc[25]), "+v"(acc[26]), "+v"(acc[27]),
                     "+v"(acc[28]), "+v"(acc[29]), "+v"(acc[30]), "+v"(acc[31]));
  }

  int gy = ty * 16 + ly, gx = tx * 16 + lx;
#pragma unroll
  for (int co = 0; co < 32; co++) {
    float val = acc[co] * bns[co] + bnb[co];
    out[((size_t)(b * CC + co) << 16) + gy * HW + gx] = fmaxf(val, 0.f);
  }
}

extern "C" void kernel_launch(void* const* d_in, const int* in_sizes, int n_in,
                              void* d_out, int out_size, void* d_ws, size_t ws_size,
                              hipStream_t stream) {
  const float* cen = (const float*)d_in[0];
  const float* trans_W = (const float*)d_in[1];
  const float* trans_b = (const float*)d_in[2];
  const float* query_W = (const float*)d_in[3];
  const float* value_W = (const float*)d_in[4];
  const float* key_W = (const float*)d_in[5];
  const float* out_W = (const float*)d_in[6];
  const float* bn_gamma = (const float*)d_in[7];
  const float* bn_beta = (const float*)d_in[8];
  const float* bn_mean = (const float*)d_in[9];
  const float* bn_var = (const float*)d_in[10];
  float* out = (float*)d_out;

  // Buffer plan (race-free, same as round-7):
  //   kv    = d_out[0, 1048576)    -- fp32 scratch; fully overwritten by k3b.
  //   srraw = ws[0, 6144)
  //   v     = ws[532480, 25698304) -- bf16
  float* kv = (float*)d_out;
  float* srraw = (float*)d_ws;
  __hip_bfloat16* v = (__hip_bfloat16*)((char*)d_ws + 532480);

  k1_trans<<<1024, 256, 0, stream>>>(cen, trans_W, trans_b, kv);
  k23_fat<<<448, 1024, 0, stream>>>(kv, query_W, key_W, srraw, cen, value_W, v);
  k3b_combine<<<512, 256, 0, stream>>>(v, srraw, out_W, bn_gamma, bn_beta, bn_mean,
                                       bn_var, out);
}

// Round 9
// 160.985 us; speedup vs baseline: 5.7401x; 5.7401x over previous
//
#include <hip/hip_runtime.h>
#include <hip/hip_bf16.h>

// ExpansionContrastModule on MI355X.
// ROUND 9: production (reps removed). Two fixes from the round-8 diagnostic:
// (1) k3b: vt row stride was 96 floats (96%32==0 -> ly drops out of bank index ->
//     8-way LDS bank conflict on EVERY float4 read/write of vt; ~4x ideal LDS cost).
//     Padded to 100 floats (VTS): all 32 banks active, ideal 8 dwords/bank.
// (2) k23_fat: K2i(192 heavy) and K3a(256 light) blocks interleaved 3:4 per group
//     of 7 bids (448=64x7) for per-CU balance (was type-partitioned: CUs 192..255
//     got one light block and idled). K2i ci-loop now #pragma unroll (batch the
//     32 kv loads instead of risking load-use serialization).
// Buffers (race-free, round-7 proven): kv=d_out[0,1MB), srraw=ws[0,6144),
// v=ws[532480,25698304). 3 launches: k1 -> k23_fat -> k3b.

#define CC 32
#define HW 256
#define KVW 64
#define VTS 100  // vt row stride in floats; 100%32=4 -> bank-conflict-free

// ---------------- K1: 5x5 stride-4 pad-2 conv + bias -> kv [2,32,64,64] ----------------
// grid 1024 = b(2) x cog(8) x y(64); 4 waves: wave w -> ci range [8w, 8w+8),
// computes all 4 co of this cog. Partials combined via LDS (4 KB).
__global__ __launch_bounds__(256, 2) void k1_trans(const float* __restrict__ cen,
                                                   const float* __restrict__ tW,
                                                   const float* __restrict__ tB,
                                                   float* __restrict__ kv) {
  __shared__ alignas(16) float part[4][4][64];  // [ci-quarter][co][x], 4 KB
  int bid = blockIdx.x;
  int b = bid >> 9, cog = (bid >> 6) & 7, y = bid & 63;
  int tid = threadIdx.x;
  int x = tid & 63;
  int w = __builtin_amdgcn_readfirstlane(tid >> 6);  // wave id 0..3 = ci quarter
  int ci0 = w * 8;
  int co0 = cog * 4;

  float acc[4] = {0.f, 0.f, 0.f, 0.f};
  const float4 z4 = {0.f, 0.f, 0.f, 0.f};

  int roff[5];
  bool rok[5];
#pragma unroll
  for (int r = 0; r < 5; r++) {
    int row = 4 * y - 2 + r;
    rok[r] = (row >= 0);
    roff[r] = (row < 0 ? 0 : row) * HW;
  }

  for (int cc4 = 0; cc4 < 8; cc4 += 4) {
    int ci = ci0 + cc4;
    const float* pc[4];
#pragma unroll
    for (int c = 0; c < 4; c++) pc[c] = cen + (size_t)(b * CC + ci + c) * 65536 + 4 * x;
    float4 A[4][5], B[4][5];
#pragma unroll
    for (int c = 0; c < 4; c++) {
#pragma unroll
      for (int r = 0; r < 5; r++) {
        A[c][r] = (x > 0) ? *(const float4*)(pc[c] + roff[r] - 4) : z4;
        B[c][r] = *(const float4*)(pc[c] + roff[r]);
      }
    }
#pragma unroll
    for (int r = 0; r < 5; r++) {
      if (!rok[r]) continue;  // block-uniform (only y==0, r<2)
#pragma unroll
      for (int c = 0; c < 4; c++) {
#pragma unroll
        for (int co = 0; co < 4; co++) {
          const float* wa = tW + ((co0 + co) * CC + ci + c) * 25 + r * 5;  // s_load
          acc[co] += wa[0] * A[c][r].z + wa[1] * A[c][r].w + wa[2] * B[c][r].x +
                     wa[3] * B[c][r].y + wa[4] * B[c][r].z;
        }
      }
    }
  }

#pragma unroll
  for (int co = 0; co < 4; co++) part[w][co][x] = acc[co];
  __syncthreads();
  {
    int co = tid >> 6, xx = tid & 63;
    float s = part[0][co][xx] + part[1][co][xx] + part[2][co][xx] + part[3][co][xx];
    kv[((b * CC + co0 + co) * KVW + y) * KVW + xx] = s + tB[co0 + co];
  }
}

// ---------------- K23 fat: 448 bids = 64 groups x (3 K2i + 4 K3a) interleaved --------
__device__ inline float wred64(float v) {
#pragma unroll
  for (int off = 1; off < 64; off <<= 1) v += __shfl_xor(v, off);
  return v;
}

__global__ __launch_bounds__(1024) void k23_fat(const float* __restrict__ kv,
                                                const float* __restrict__ qW,
                                                const float* __restrict__ kW,
                                                float* __restrict__ srraw,
                                                const float* __restrict__ cen,
                                                const float* __restrict__ vW,
                                                __hip_bfloat16* __restrict__ v) {
  __shared__ alignas(16) float kl[4096];  // k2i: full 64x64 k_i map (16 KB)
  __shared__ float wredl[16][18];         // k2i: per-wave D[8], M[8], Q2[16]
  int bid = blockIdx.x;
  int tid = threadIdx.x;
  // Interleave: group g = bid/7; slots 0..2 -> K2i id g*3+s; slots 3..6 -> K3a id g*4+s-3.
  int g = bid / 7, s = bid - g * 7;

  if (s < 3) {
    // ---- K2i body: block (bc, i) ----
    int k2id = g * 3 + s;  // 0..191
    int bc = k2id / 3, i = k2id - bc * 3;
    int b = bc >> 5, c = bc & 31;
    int lane = tid & 63, w = tid >> 6;  // w 0..15
    int xx = tid & 63;
    int ybase = tid >> 6;

    float qreg[4];
#pragma unroll
    for (int r = 0; r < 4; r++) {
      int px = r * 1024 + tid;  // row = r*16 + ybase, col = xx
      float q = 0.f, kk = 0.f;
#pragma unroll
      for (int ci = 0; ci < CC; ci++) {
        float val = kv[(b * CC + ci) * 4096 + px];
        q += qW[c * CC + ci] * val;
        kk += kW[(i * CC + c) * CC + ci] * val;
      }
      qreg[r] = q;
      kl[px] = kk;
    }
    __syncthreads();

    float q2 = 0.f;
#pragma unroll
    for (int r = 0; r < 4; r++) q2 += qreg[r] * qreg[r];
    q2 = wred64(q2);
    if (lane == 0) wredl[w][16] = q2;

    constexpr int DYt[8] = {-1, -1, -1, 0, 1, 1, 1, 0};
    constexpr int DXt[8] = {-1, 0, 1, 1, 1, 0, -1, -1};
    const int d = 1 << i;
#pragma unroll
    for (int n = 0; n < 8; n++) {
      const int dy = DYt[n], dx = DXt[n];
      int xn = xx + dx * d;
      bool xok = (xn >= 0 && xn < KVW);
      float dacc = 0.f, macc = 0.f;
#pragma unroll
      for (int r = 0; r < 4; r++) {
        int yy = r * 16 + ybase;
        int px = yy * KVW + xx;
        float kc = kl[px];
        int yn = yy + dy * d;
        float kn = (xok && yn >= 0 && yn < KVW) ? kl[yn * KVW + xn] : 0.f;
        float df = kc - kn;
        dacc += qreg[r] * df;
        macc += df * df;
      }
      dacc = wred64(dacc);
      macc = wred64(macc);
      if (lane == 0) {
        wredl[w][n] = dacc;
        wredl[w][8 + n] = macc;
      }
    }
    __syncthreads();

    // Finalize this block's 8 raw cosine sims (D, M, Q all local; Q bitwise
    // identical across i since qreg and the summation order don't depend on i).
    if (tid < 8) {
      float D = 0.f, M = 0.f, Q = 0.f;
      for (int w2 = 0; w2 < 16; w2++) {
        D += wredl[w2][tid];
        M += wredl[w2][8 + tid];
        Q += wredl[w2][16];
      }
      float sr = D / (fmaxf(sqrtf(M), 1e-12f) * fmaxf(sqrtf(Q), 1e-12f));
      srraw[bc * 24 + i * 8 + tid] = sr;
    }
  } else {
    // ---- K3a body: 4 virtual 256-thread sub-blocks per bid ----
    int k3id = g * 4 + (s - 3);      // 0..255
    int vb = k3id * 4 + (tid >> 8);  // virtual block 0..1023
    int b = vb >> 9, blk = vb & 511;
    int lane = tid & 63;
    int cg = __builtin_amdgcn_readfirstlane((tid >> 6) & 3);  // wave-uniform c group
    int px = blk * 128 + lane * 2;

    float2 cr[CC];
#pragma unroll
    for (int ci = 0; ci < CC; ci++)
      cr[ci] = *(const float2*)(cen + (size_t)(b * CC + ci) * 65536 + px);

#pragma unroll
    for (int i = 0; i < 3; i++) {
#pragma unroll
      for (int cc = 0; cc < 8; cc++) {
        int c = cg * 8 + cc;
        const float* wp = vW + (i * CC + c) * CC;  // uniform -> s_load
        float a0 = 0.f, a1 = 0.f;
#pragma unroll
        for (int ci = 0; ci < CC; ci++) {
          a0 += wp[ci] * cr[ci].x;
          a1 += wp[ci] * cr[ci].y;
        }
        __hip_bfloat16 h0 = __float2bfloat16(a0);
        __hip_bfloat16 h1 = __float2bfloat16(a1);
        unsigned int pk = (unsigned int)(*(unsigned short*)&h0) |
                          ((unsigned int)(*(unsigned short*)&h1) << 16);
        *(unsigned int*)((unsigned short*)v + (((size_t)((i * 2 + b) * CC + c)) << 16) +
                         px) = pk;
      }
    }
  }
}

// ---------------- K3b: score l2norm + combine + out conv + BN + ReLU -----
__global__ __launch_bounds__(256) void k3b_combine(const __hip_bfloat16* __restrict__ v,
                                                   const float* __restrict__ srraw,
                                                   const float* __restrict__ oW,
                                                   const float* __restrict__ gamma,
                                                   const float* __restrict__ beta,
                                                   const float* __restrict__ mean,
                                                   const float* __restrict__ var,
                                                   float* __restrict__ out) {
  // vt: [i][r 0..23][col 0..23][cp 0..3] with padded row stride VTS=100 floats
  // (100%32=4 -> row index shifts banks by 4; all 32 banks active on float4 reads).
  __shared__ alignas(16) float vt[3 * 24 * VTS];  // 28.8 KB
  __shared__ alignas(16) float sl[27][32];        // 0..23: s[j][c]; 24..26: S_i[c]
  __shared__ alignas(16) float owl[32][32];       // [co][c]
  __shared__ float bns[32], bnb[32];

  int bid = blockIdx.x;
  int b = bid >> 8, tile = bid & 255;
  int ty = tile >> 4, tx = tile & 15;
  int tid = threadIdx.x;
  int ly = tid >> 4, lx = tid & 15;

  // Raw cosine sims [24 j][32 c] for this b.
  for (int f = tid; f < 768; f += 256) {
    int j = f >> 5, c = f & 31;
    sl[j][c] = srraw[(b * CC + c) * 24 + j];
  }
  for (int f = tid; f < 1024; f += 256) owl[f >> 5][f & 31] = oW[f];
  if (tid < 32) {
    float inv = rsqrtf(var[tid] + 1e-5f);
    float sc = gamma[tid] * inv;
    bns[tid] = sc;
    bnb[tid] = beta[tid] - mean[tid] * sc;
  }
  __syncthreads();
  if (tid < 32) {
    float r2 = 0.f;
#pragma unroll
    for (int j = 0; j < 24; j++) {
      float s = sl[j][tid];
      r2 += s * s;
    }
    float dn = fmaxf(sqrtf(r2), 1e-12f);
#pragma unroll
    for (int j = 0; j < 24; j++) sl[j][tid] /= dn;
#pragma unroll
    for (int i = 0; i < 3; i++) {
      float s = 0.f;
      for (int n = 0; n < 8; n++) s += sl[i * 8 + n][tid];
      sl[24 + i][tid] = s;
    }
  }

  int ldsoff[4], pxoff[4], ibase[4];
  bool okp[4];
#pragma unroll
  for (int it = 0; it < 4; it++) {
    int p = tid + it * 256;
    bool act = (p < 864);
    int pp = act ? p : 0;
    int i = pp / 288;
    int rem = pp - i * 288;
    int r = rem / 12;
    int col = (rem - r * 12) * 2;
    int gy = ty * 16 + r - 4, gx = tx * 16 + col - 4;
    okp[it] = act && gy >= 0 && gy < HW && gx >= 0 && gx < HW;
    pxoff[it] = gy * HW + gx;
    ibase[it] = (i * 2 + b) * CC;
    ldsoff[it] = (i * 24 + r) * VTS + col * 4;  // padded stride
  }

  constexpr int DYt[8] = {-1, -1, -1, 0, 1, 1, 1, 0};
  constexpr int DXt[8] = {-1, 0, 1, 1, 1, 0, -1, -1};

  float acc[32];
#pragma unroll
  for (int co = 0; co < 32; co++) acc[co] = 0.f;

  unsigned int pf[4][4];
  const unsigned short* vs = (const unsigned short*)v;

#pragma unroll
  for (int it = 0; it < 4; it++)
#pragma unroll
    for (int cp = 0; cp < 4; cp++)
      pf[it][cp] = okp[it]
                       ? *(const unsigned int*)(vs + (((size_t)(ibase[it] + cp)) << 16) +
                                                pxoff[it])
                       : 0u;

  for (int cg = 0; cg < 8; cg++) {
    __syncthreads();
#pragma unroll
    for (int it = 0; it < 4; it++) {
      if (it == 3 && tid >= 96) continue;  // p >= 864
      float4 lo, hi;
      lo.x = __uint_as_float(pf[it][0] << 16);
      lo.y = __uint_as_float(pf[it][1] << 16);
      lo.z = __uint_as_float(pf[it][2] << 16);
      lo.w = __uint_as_float(pf[it][3] << 16);
      hi.x = __uint_as_float(pf[it][0] & 0xffff0000u);
      hi.y = __uint_as_float(pf[it][1] & 0xffff0000u);
      hi.z = __uint_as_float(pf[it][2] & 0xffff0000u);
      hi.w = __uint_as_float(pf[it][3] & 0xffff0000u);
      *(float4*)&vt[ldsoff[it]] = lo;
      *(float4*)&vt[ldsoff[it] + 4] = hi;
    }
    if (cg < 7) {
      int cb = (cg + 1) * 4;
#pragma unroll
      for (int it = 0; it < 4; it++)
#pragma unroll
        for (int cp = 0; cp < 4; cp++)
          pf[it][cp] = okp[it] ? *(const unsigned int*)(vs +
                                                        (((size_t)(ibase[it] + cb + cp))
                                                         << 16) +
                                                        pxoff[it])
                               : 0u;
    }
    __syncthreads();

    float4 pre = {0.f, 0.f, 0.f, 0.f};
#pragma unroll
    for (int i = 0; i < 3; i++) {
      const int d = 1 << i;
      float4 S4 = *(const float4*)&sl[24 + i][cg * 4];
      float4 ctr = *(const float4*)&vt[(i * 24 + (ly + 4)) * VTS + (lx + 4) * 4];
      pre.x += S4.x * ctr.x;
      pre.y += S4.y * ctr.y;
      pre.z += S4.z * ctr.z;
      pre.w += S4.w * ctr.w;
#pragma unroll
      for (int n = 0; n < 8; n++) {
        float4 sj = *(const float4*)&sl[i * 8 + n][cg * 4];
        float4 nb = *(const float4*)&vt[(i * 24 + (ly + 4 + DYt[n] * d)) * VTS +
                                        (lx + 4 + DXt[n] * d) * 4];
        pre.x -= sj.x * nb.x;
        pre.y -= sj.y * nb.y;
        pre.z -= sj.z * nb.z;
        pre.w -= sj.w * nb.w;
      }
    }
#pragma unroll
    for (int co = 0; co < 32; co++) {
      float4 ow = *(const float4*)&owl[co][cg * 4];
      acc[co] += ow.x * pre.x + ow.y * pre.y + ow.z * pre.z + ow.w * pre.w;
    }
  }

  int gy = ty * 16 + ly, gx = tx * 16 + lx;
#pragma unroll
  for (int co = 0; co < 32; co++) {
    float val = acc[co] * bns[co] + bnb[co];
    out[((size_t)(b * CC + co) << 16) + gy * HW + gx] = fmaxf(val, 0.f);
  }
}

extern "C" void kernel_launch(void* const* d_in, const int* in_sizes, int n_in,
                              void* d_out, int out_size, void* d_ws, size_t ws_size,
                              hipStream_t stream) {
  const float* cen = (const float*)d_in[0];
  const float* trans_W = (const float*)d_in[1];
  const float* trans_b = (const float*)d_in[2];
  const float* query_W = (const float*)d_in[3];
  const float* value_W = (const float*)d_in[4];
  const float* key_W = (const float*)d_in[5];
  const float* out_W = (const float*)d_in[6];
  const float* bn_gamma = (const float*)d_in[7];
  const float* bn_beta = (const float*)d_in[8];
  const float* bn_mean = (const float*)d_in[9];
  const float* bn_var = (const float*)d_in[10];
  float* out = (float*)d_out;

  // Buffer plan (race-free, same as round-7):
  //   kv    = d_out[0, 1048576)    -- fp32 scratch; fully overwritten by k3b.
  //   srraw = ws[0, 6144)
  //   v     = ws[532480, 25698304) -- bf16
  float* kv = (float*)d_out;
  float* srraw = (float*)d_ws;
  __hip_bfloat16* v = (__hip_bfloat16*)((char*)d_ws + 532480);

  k1_trans<<<1024, 256, 0, stream>>>(cen, trans_W, trans_b, kv);
  k23_fat<<<448, 1024, 0, stream>>>(kv, query_W, key_W, srraw, cen, value_W, v);
  k3b_combine<<<512, 256, 0, stream>>>(v, srraw, out_W, bn_gamma, bn_beta, bn_mean,
                                       bn_var, out);
}